// Round 10
// baseline (162.194 us; speedup 1.0000x reference)
//
#include <hip/hip_runtime.h>

#define T_LEN 32768
#define B_N   64
#define SEG   64
#define WARM  64
#define NSEG  (T_LEN / SEG)        // 512 segments/sample
#define SPW   32                   // streams per wave: 2 groups x 16 MFMA cols
#define WPS   (NSEG / SPW)         // 16 waves/sample -> grid 1024 (4 blk/CU, 1 wave/SIMD)
#define CSKIP (WARM / 32)          // 2 warm chunks
#define NCH   (CSKIP + SEG / 32)   // 4 chunks of 32 steps
#define XROW  33                   // x LDS row stride (conflict-free)
#define YROW  33                   // y LDS row stride

typedef __fp16 half2v __attribute__((ext_vector_type(2)));
typedef __fp16 half8  __attribute__((ext_vector_type(8)));
typedef float  f32x4  __attribute__((ext_vector_type(4)));

#define MFMA16(a, b, c) __builtin_amdgcn_mfma_f32_16x16x32_f16((a), (b), (c), 0, 0, 0)

union BU { half2v h2[4]; half8 h8; int i4[4]; };

// Cross-half partner exchange lane[i] <-> lane[i^32] (r28: full-rate VALU
// permlane32_swap; r[0]^r[1]^P -> partner under either operand-order reading).
#if __has_builtin(__builtin_amdgcn_permlane32_swap)
typedef int int2v __attribute__((ext_vector_type(2)));
#define XHALF(P) ({ int2v r_ = __builtin_amdgcn_permlane32_swap((P), (P), false, false); \
                    (int)(r_[0] ^ r_[1] ^ (P)); })
#else
#define XHALF(P) __shfl_xor((P), 32, 64)
#endif

// Row permutation rho (involution): swaps 4..7 <-> 8..11. With the verified
// 16x16 D-layout (col=lane&15, row=(lane>>4)*4+reg), A-rows permuted by rho
// make lane q own H components rho(4q..4q+3), so the B-fragment rebuild is
// own-quad + (lane^32)-quad — one XHALF pair, zero other cross-lane ops.
__device__ __forceinline__ int rho(int v) {
    const int qq = v >> 2;
    return (qq == 1) ? v + 4 : (qq == 2) ? v - 4 : v;
}

// r29: DUAL-GROUP WAVES. r9 measured 62% VALUBusy at 2 waves/SIMD — the two
// waves' stall windows align (same code, chunk-synced), leaving ~500 of
// 1286 cy/slot idle. A/B fragments + all constants are PER-SAMPLE, so a
// second 16-stream group shares them for +4 persistent regs: one wave now
// runs 32 streams (two independent chains the compiler interleaves
// instruction-level). Grid 1024 (1 wave/SIMD); issue floor ~500 cy/step.
// launch_bounds (64,1): dual-group live set (~170 VGPR) must not be capped
// at 128 (r4 spill lesson). r27 16x16x32 shape + r28 permlane kept.
// Segment-parallel correctness (r12) unchanged: WARM=64, boundary re-pin.
#define GRU_STEP(TT) do {                                                      \
    half2v t0_ = __builtin_amdgcn_cvt_pkrtz(Hd[0], Hd[1]);                     \
    half2v t1_ = __builtin_amdgcn_cvt_pkrtz(Hd[2], Hd[3]);                     \
    half2v u0_ = __builtin_amdgcn_cvt_pkrtz(He[0], He[1]);                     \
    half2v u1_ = __builtin_amdgcn_cvt_pkrtz(He[2], He[3]);                     \
    int p0_, p1_, q0_, q1_;                                                    \
    __builtin_memcpy(&p0_, &t0_, 4); __builtin_memcpy(&p1_, &t1_, 4);          \
    __builtin_memcpy(&q0_, &u0_, 4); __builtin_memcpy(&q1_, &u1_, 4);          \
    const int pp0_ = XHALF(p0_);                                               \
    const int pp1_ = XHALF(p1_);                                               \
    const int qq0_ = XHALF(q0_);                                               \
    const int qq1_ = XHALF(q1_);                                               \
    half2v tx_ = __builtin_amdgcn_cvt_pkrtz(xcur, 1.0f);                       \
    half2v ty_ = __builtin_amdgcn_cvt_pkrtz(xcur2, 1.0f);                      \
    int xw_, yw_;                                                              \
    __builtin_memcpy(&xw_, &tx_, 4); __builtin_memcpy(&yw_, &ty_, 4);          \
    BU Bu_, Bv_;                                                               \
    Bu_.i4[0] = qlt2 ? p0_ : (isq2 ? xw_ : 0);                                 \
    Bu_.i4[1] = qlt2 ? p1_ : 0;                                                \
    Bu_.i4[2] = qlt2 ? pp0_ : 0;                                               \
    Bu_.i4[3] = qlt2 ? pp1_ : 0;                                               \
    Bv_.i4[0] = qlt2 ? q0_ : (isq2 ? yw_ : 0);                                 \
    Bv_.i4[1] = qlt2 ? q1_ : 0;                                                \
    Bv_.i4[2] = qlt2 ? qq0_ : 0;                                               \
    Bv_.i4[3] = qlt2 ? qq1_ : 0;                                               \
    const f32x4 d1 = MFMA16(A1u.h8, Bu_.h8, zero4);                            \
    const f32x4 d2 = MFMA16(A2u.h8, Bu_.h8, zero4);                            \
    const f32x4 d3 = MFMA16(A3u.h8, Bu_.h8, zero4);                            \
    const f32x4 d4 = MFMA16(A4u.h8, Bu_.h8, zero4);                            \
    const f32x4 e1 = MFMA16(A1u.h8, Bv_.h8, zero4);                            \
    const f32x4 e2 = MFMA16(A2u.h8, Bv_.h8, zero4);                            \
    const f32x4 e3 = MFMA16(A3u.h8, Bv_.h8, zero4);                            \
    const f32x4 e4 = MFMA16(A4u.h8, Bv_.h8, zero4);                            \
    const int nx_ = ((TT) + 1 < 32) ? (TT) + 1 : 31;                           \
    const float xnx_  = xr[nx_];                                               \
    const float xnx2_ = xr2[nx_];                                              \
    _Pragma("unroll")                                                          \
    for (int j = 0; j < 4; ++j) {                                              \
        const float ur  = __builtin_amdgcn_rcpf(1.f + __builtin_amdgcn_exp2f(d1[j]));     \
        const float ui  = __builtin_amdgcn_rcpf(1.f + __builtin_amdgcn_exp2f(d2[j]));     \
        const float tno = fmaf(ur, d3[j], fmaf(xcur, wihN4[j], bihN4[j]));     \
        const float un  = __builtin_amdgcn_rcpf(1.f + __builtin_amdgcn_exp2f(tno));       \
        Hd[j] = fmaf(ui, fmaf(-2.f, un, Hd[j]), un + un);                      \
    }                                                                          \
    _Pragma("unroll")                                                          \
    for (int j = 0; j < 4; ++j) {                                              \
        const float ur  = __builtin_amdgcn_rcpf(1.f + __builtin_amdgcn_exp2f(e1[j]));     \
        const float ui  = __builtin_amdgcn_rcpf(1.f + __builtin_amdgcn_exp2f(e2[j]));     \
        const float tno = fmaf(ur, e3[j], fmaf(xcur2, wihN4[j], bihN4[j]));    \
        const float un  = __builtin_amdgcn_rcpf(1.f + __builtin_amdgcn_exp2f(tno));       \
        He[j] = fmaf(ui, fmaf(-2.f, un, He[j]), un + un);                      \
    }                                                                          \
    if (doy) {                                                                 \
        ylds[m16*YROW        + (((TT) + 31) & 31)] = d4[0];                    \
        ylds[(16+m16)*YROW   + (((TT) + 31) & 31)] = e4[0];                    \
    }                                                                          \
    xcur = xnx_;  xcur2 = xnx2_;                                               \
    __builtin_amdgcn_sched_barrier(0);                                         \
} while (0)

// x staging: 32 streams x 32 steps per chunk; lane ln>>1 = row, 16 floats
#define STAGE_X(CC) do {                                                       \
    const int row_ = ln >> 1, cb_ = (ln & 1) * 16;                             \
    const int xb_ = b*T_LEN + (SPW*w + row_)*SEG - WARM + (CC)*32 + cb_;       \
    float v_[16];                                                              \
    if (xb_ >= 0) {                                                            \
        _Pragma("unroll")                                                      \
        for (int j = 0; j < 4; ++j) {                                          \
            const float4 t_ = *(const float4*)(x + xb_ + 4*j);                 \
            v_[4*j+0]=t_.x; v_[4*j+1]=t_.y; v_[4*j+2]=t_.z; v_[4*j+3]=t_.w;    \
        }                                                                      \
    } else {                                                                   \
        _Pragma("unroll")                                                      \
        for (int i = 0; i < 16; ++i) {                                         \
            int id_ = xb_ + i; id_ = (id_ < 0) ? 0 : id_;                      \
            v_[i] = x[id_];                                                    \
        }                                                                      \
    }                                                                          \
    _Pragma("unroll")                                                          \
    for (int i = 0; i < 16; ++i) xlds[row_*XROW + cb_ + i] = v_[i];            \
} while (0)

__global__ __launch_bounds__(64, 1) void hyper_gru_kernel(
    const float* __restrict__ x,     const float* __restrict__ c,    const float* __restrict__ h0,
    const float* __restrict__ w1,    const float* __restrict__ b1,
    const float* __restrict__ w2,    const float* __restrict__ b2,
    const float* __restrict__ pihw,  const float* __restrict__ pihb,
    const float* __restrict__ phhw,  const float* __restrict__ phhb,
    const float* __restrict__ pbihw, const float* __restrict__ pbihb,
    const float* __restrict__ pbhhw, const float* __restrict__ pbhhb,
    const float* __restrict__ oww,   const float* __restrict__ owb,
    float* __restrict__ out)
{
    const int blk = blockIdx.x;
    const int b   = blk / WPS;         // sample
    const int w   = blk - b * WPS;     // wave index within sample (16 waves)
    const int ln  = threadIdx.x;
    const int m16 = ln & 15;           // A row / B,D col (stream id within group)
    const int q   = ln >> 4;           // k-group (A/B) and D row-group
    const bool qlt2 = (q < 2);
    const bool isq2 = (q == 2);
    const int pim = rho(m16);          // permuted gate component for A row m16

    __shared__ float xlds[SPW * XROW];
    __shared__ float ylds[SPW * YROW];
    __shared__ float sp[2][3][16];     // k-half partial row sums (r,i,n)

    // ---- hypernetwork: cond MLP -> a2[8] (uniform; redundant per lane) ----
    float cv[8], a1m[8], a2m[8];
    #pragma unroll
    for (int n = 0; n < 8; ++n) cv[n] = c[b*8 + n];
    #pragma unroll
    for (int mm = 0; mm < 8; ++mm) {
        float sv = b1[mm];
        #pragma unroll
        for (int n = 0; n < 8; ++n) sv = fmaf(cv[n], w1[mm*8 + n], sv);
        a1m[mm] = (sv >= 0.f) ? sv : 0.1f * sv;
    }
    #pragma unroll
    for (int mm = 0; mm < 8; ++mm) {
        float sv = b2[mm];
        #pragma unroll
        for (int k = 0; k < 8; ++k) sv = fmaf(a1m[k], w2[mm*8 + k], sv);
        a2m[mm] = (sv >= 0.f) ? sv : 0.1f * sv;
    }
    auto proj = [&](const float* W, const float* Bv, int row) {
        float sv = Bv[row];
        #pragma unroll
        for (int mm = 0; mm < 8; ++mm) sv = fmaf(a2m[mm], W[row*8 + mm], sv);
        return sv;
    };

    // Scales folded in: r,i: -log2e (sigmoid = rcp(1+exp2(acc)));
    //                   n:   -2log2e (tanh = 2*rcp(1+exp2(acc)) - 1)
    const float SC1 = -1.44269504f, SC2 = -2.88539008f;

    // output weight fold
    float sumow = 0.f;
    #pragma unroll
    for (int k = 0; k < 16; ++k) sumow += oww[k];
    const float obv = owb[0] - sumow;

    // ---- A fragments: lane holds A[row=m16, k=8q+i] ----
    // k<16: W_hh columns (rho-permuted rows). k=16: x coeff. k=17: bias. rest 0.
    float A1f[8] = {}, A2f[8] = {}, A3f[8] = {}, A4f[8] = {};
    if (qlt2) {
        float p1 = 0.f, p2 = 0.f, p3 = 0.f;
        #pragma unroll
        for (int i = 0; i < 8; ++i) {
            const int k = 8*q + i;
            A1f[i] = SC1 * proj(phhw, phhb, k*48 + pim);        p1 += A1f[i];
            A2f[i] = SC1 * proj(phhw, phhb, k*48 + 16 + pim);   p2 += A2f[i];
            A3f[i] = SC2 * proj(phhw, phhb, k*48 + 32 + pim);   p3 += A3f[i];
            A4f[i] = (m16 == 0) ? oww[k] : 0.f;
            __builtin_amdgcn_sched_barrier(0);   // bound load-hoisting (anti-spill)
        }
        sp[q][0][m16] = p1;  sp[q][1][m16] = p2;  sp[q][2][m16] = p3;
    }
    __syncthreads();
    if (isq2) {
        const float sWr = sp[0][0][m16] + sp[1][0][m16];
        const float sWi = sp[0][1][m16] + sp[1][1][m16];
        const float sWn = sp[0][2][m16] + sp[1][2][m16];
        A1f[0] = SC1 * proj(pihw, pihb, pim);
        A1f[1] = SC1 * (proj(pbihw, pbihb, pim) + proj(pbhhw, pbhhb, pim)) - sWr;
        A2f[0] = SC1 * proj(pihw, pihb, 16 + pim);
        A2f[1] = SC1 * (proj(pbihw, pbihb, 16 + pim) + proj(pbhhw, pbhhb, 16 + pim)) - sWi;
        A3f[1] = SC2 * proj(pbhhw, pbhhb, 32 + pim) - sWn;     // biasAN (r-multiplied)
        A4f[1] = (m16 == 0) ? obv : 0.f;
        __builtin_amdgcn_sched_barrier(0);
    }
    BU A1u, A2u, A3u, A4u;
    #pragma unroll
    for (int r = 0; r < 4; ++r) {
        A1u.h2[r] = __builtin_amdgcn_cvt_pkrtz(A1f[2*r], A1f[2*r+1]);
        A2u.h2[r] = __builtin_amdgcn_cvt_pkrtz(A2f[2*r], A2f[2*r+1]);
        A3u.h2[r] = __builtin_amdgcn_cvt_pkrtz(A3f[2*r], A3f[2*r+1]);
        A4u.h2[r] = __builtin_amdgcn_cvt_pkrtz(A4f[2*r], A4f[2*r+1]);
    }

    // n-gate x-projection stays on VALU; component cj = rho(4q+j).
    float wihN4[4], bihN4[4], owN4[4];
    #pragma unroll
    for (int j = 0; j < 4; ++j) {
        const int cj = rho(4*q + j);
        wihN4[j] = SC2 * proj(pihw, pihb, 32 + cj);
        bihN4[j] = SC2 * proj(pbihw, pbihb, 32 + cj);
        owN4[j]  = oww[cj];
    }
    __builtin_amdgcn_sched_barrier(0);

    const f32x4 zero4 = {0.f, 0.f, 0.f, 0.f};

    // ---- state: H = h+1; group0 = streams 32w+m16, group1 = 32w+16+m16.
    // All speculate 1; sample stream 0 (w0, group0, m16=0) re-pinned at the
    // warm->main boundary ----
    float Hd[4], He[4];
    #pragma unroll
    for (int j = 0; j < 4; ++j) { Hd[j] = 1.f; He[j] = 1.f; }

    STAGE_X(0);
    __syncthreads();

    for (int cc = 0; cc < NCH; ++cc) {
        if (cc == CSKIP && w == 0 && m16 == 0) {
            #pragma unroll
            for (int j = 0; j < 4; ++j)
                Hd[j] = h0[b*16 + rho(4*q + j)] + 1.f;
        }
        const bool doy = (cc >= CSKIP) && (ln < 16);
        const float* xr  = xlds + m16*XROW;
        const float* xr2 = xlds + (16 + m16)*XROW;
        float xcur  = xr[0];
        float xcur2 = xr2[0];
        #pragma unroll
        for (int tt = 0; tt < 32; ++tt) GRU_STEP(tt);

        if (cc >= CSKIP) {
            // slot-31 y from current H: obv + sum_h ow[h]*H[h] (4 lanes/stream)
            float p = 0.f, p2g = 0.f;
            #pragma unroll
            for (int j = 0; j < 4; ++j) {
                p   = fmaf(owN4[j], Hd[j], p);
                p2g = fmaf(owN4[j], He[j], p2g);
            }
            p   += __shfl_xor(p, 16, 64);
            p   += __shfl_xor(p, 32, 64);
            p2g += __shfl_xor(p2g, 16, 64);
            p2g += __shfl_xor(p2g, 32, 64);
            if (ln < 16) {
                ylds[m16*YROW + 31]        = obv + p;
                ylds[(16 + m16)*YROW + 31] = obv + p2g;
            }
        }
        __syncthreads();           // ylds complete; xlds reads done

        if (cc >= CSKIP) {
            // write 32 streams x 32 steps; lane ln>>1 = row, 16 floats
            const int row_ = ln >> 1, cb_ = (ln & 1) * 16;
            const int tb = b*T_LEN + (SPW*w + row_)*SEG + (cc - CSKIP)*32 + cb_;
            #pragma unroll
            for (int j = 0; j < 4; ++j) {
                float4 o;
                o.x = ylds[row_*YROW + cb_ + 4*j + 0];
                o.y = ylds[row_*YROW + cb_ + 4*j + 1];
                o.z = ylds[row_*YROW + cb_ + 4*j + 2];
                o.w = ylds[row_*YROW + cb_ + 4*j + 3];
                *(float4*)(out + tb + 4*j) = o;
            }
        }
        if (cc + 1 < NCH) STAGE_X(cc + 1);
        __syncthreads();           // xlds ready for next chunk
    }

    // h_last [B,1,R]: last stream = (w=WPS-1, group1, m16=15); exact f32 state
    if (w == WPS - 1 && m16 == 15) {
        #pragma unroll
        for (int j = 0; j < 4; ++j)
            out[B_N * T_LEN + b*16 + rho(4*q + j)] = He[j] - 1.f;
    }
}

extern "C" void kernel_launch(void* const* d_in, const int* in_sizes, int n_in,
                              void* d_out, int out_size, void* d_ws, size_t ws_size,
                              hipStream_t stream) {
    (void)in_sizes; (void)n_in; (void)d_ws; (void)ws_size; (void)out_size;
    hipLaunchKernelGGL(hyper_gru_kernel, dim3(B_N * WPS), dim3(64), 0, stream,
        (const float*)d_in[0],  (const float*)d_in[1],  (const float*)d_in[2],
        (const float*)d_in[3],  (const float*)d_in[4],  (const float*)d_in[5],  (const float*)d_in[6],
        (const float*)d_in[7],  (const float*)d_in[8],  (const float*)d_in[9],  (const float*)d_in[10],
        (const float*)d_in[11], (const float*)d_in[12], (const float*)d_in[13], (const float*)d_in[14],
        (const float*)d_in[15], (const float*)d_in[16],
        (float*)d_out);
}

// Round 11
// 150.275 us; speedup vs baseline: 1.0793x; 1.0793x over previous
//
#include <hip/hip_runtime.h>

#define T_LEN 32768
#define B_N   64
#define SEG   64
#define WARM  64
#define NSEG  (T_LEN / SEG)        // 512 segments/sample
#define SPW   16                   // streams per wave (16x16 MFMA cols)
#define WPS   (NSEG / SPW)         // 32 waves/sample -> grid 2048 (8 blk/CU, 2 waves/SIMD)
#define CSKIP (WARM / 32)          // 2 warm chunks
#define NCH   (CSKIP + SEG / 32)   // 4 chunks of 32 steps
#define XROW  33                   // x LDS row stride (conflict-free)
#define YROW  33                   // y LDS row stride

typedef __fp16 half2v __attribute__((ext_vector_type(2)));
typedef __fp16 half8  __attribute__((ext_vector_type(8)));
typedef float  f32x4  __attribute__((ext_vector_type(4)));

#define MFMA16(a, b, c) __builtin_amdgcn_mfma_f32_16x16x32_f16((a), (b), (c), 0, 0, 0)

union BU { half2v h2[4]; half8 h8; int i4[4]; };

// Cross-half partner exchange lane[i] <-> lane[i^32] (r28: full-rate VALU
// permlane32_swap; r[0]^r[1]^P -> partner under either operand-order reading).
#if __has_builtin(__builtin_amdgcn_permlane32_swap)
typedef int int2v __attribute__((ext_vector_type(2)));
#define XHALF(P) ({ int2v r_ = __builtin_amdgcn_permlane32_swap((P), (P), false, false); \
                    (int)(r_[0] ^ r_[1] ^ (P)); })
#else
#define XHALF(P) __shfl_xor((P), 32, 64)
#endif

// Row permutation rho (involution): swaps 4..7 <-> 8..11. With the verified
// 16x16 D-layout (col=lane&15, row=(lane>>4)*4+reg), A-rows permuted by rho
// make lane q own H components rho(4q..4q+3), so the B-fragment rebuild is
// own-quad + (lane^32)-quad — one XHALF pair, zero other cross-lane ops.
__device__ __forceinline__ int rho(int v) {
    const int qq = v >> 2;
    return (qq == 1) ? v + 4 : (qq == 2) ? v - 4 : v;
}

// r31: REVERT to r9 (best: 68.6 us) + PHASE STAGGER + FREE SCHEDULING.
// r10 lesson: in-wave dual-chain ILP raises issue 12% and drops fill —
// HW 2-wave interleave beats compiler static interleave. r9's residual
// cost is ~486 cy/step-slot where BOTH waves stall simultaneously: the
// two co-resident waves (different blocks, no shared barrier) run an
// identical ~1050-cy-period loop, so an initial phase offset persists —
// a one-time s_sleep keyed on block index pushes pairs toward anti-phase
// so stall gaps become complementary. Also removed: the per-step
// sched_barrier(0) (anti-spill guard from the 32x32 era; live set is now
// tiny, cap 256 @ bounds(64,2)) — lets the scheduler overlap step t's
// transcendental tail with step t+1's front (cvt/B-assembly needs only Hd).
// r27 16x16x32 shape + r28 permlane kept. Segment-parallel correctness
// (r12) unchanged: WARM=64, boundary re-pin.
#define GRU_STEP(TT) do {                                                      \
    half2v t0_ = __builtin_amdgcn_cvt_pkrtz(Hd[0], Hd[1]);                     \
    half2v t1_ = __builtin_amdgcn_cvt_pkrtz(Hd[2], Hd[3]);                     \
    int p0_, p1_;                                                              \
    __builtin_memcpy(&p0_, &t0_, 4); __builtin_memcpy(&p1_, &t1_, 4);          \
    const int pp0_ = XHALF(p0_);                                               \
    const int pp1_ = XHALF(p1_);                                               \
    half2v tx_ = __builtin_amdgcn_cvt_pkrtz(xcur, 1.0f);                       \
    int xw_; __builtin_memcpy(&xw_, &tx_, 4);                                  \
    BU Bu_;                                                                    \
    Bu_.i4[0] = qlt2 ? p0_ : (isq2 ? xw_ : 0);                                 \
    Bu_.i4[1] = qlt2 ? p1_ : 0;                                                \
    Bu_.i4[2] = qlt2 ? pp0_ : 0;                                               \
    Bu_.i4[3] = qlt2 ? pp1_ : 0;                                               \
    const f32x4 d1 = MFMA16(A1u.h8, Bu_.h8, zero4);                            \
    const f32x4 d2 = MFMA16(A2u.h8, Bu_.h8, zero4);                            \
    const f32x4 d3 = MFMA16(A3u.h8, Bu_.h8, zero4);                            \
    const f32x4 d4 = MFMA16(A4u.h8, Bu_.h8, zero4);                            \
    const float xnx_ = xr[((TT) + 1 < 32) ? (TT) + 1 : 31];                    \
    _Pragma("unroll")                                                          \
    for (int j = 0; j < 4; ++j) {                                              \
        const float ur  = __builtin_amdgcn_rcpf(1.f + __builtin_amdgcn_exp2f(d1[j]));     \
        const float ui  = __builtin_amdgcn_rcpf(1.f + __builtin_amdgcn_exp2f(d2[j]));     \
        const float tno = fmaf(ur, d3[j], fmaf(xcur, wihN4[j], bihN4[j]));     \
        const float un  = __builtin_amdgcn_rcpf(1.f + __builtin_amdgcn_exp2f(tno));       \
        Hd[j] = fmaf(ui, fmaf(-2.f, un, Hd[j]), un + un);                      \
    }                                                                          \
    if (doy) ylds[m16*YROW + (((TT) + 31) & 31)] = d4[0];                      \
    xcur = xnx_;                                                               \
} while (0)

// x staging: 16 streams x 32 steps per chunk; lane ln>>2 = row, 8 floats
#define STAGE_X(CC) do {                                                       \
    const int row_ = ln >> 2, cb_ = (ln & 3) * 8;                              \
    const int xb_ = b*T_LEN + (SPW*w + row_)*SEG - WARM + (CC)*32 + cb_;       \
    float v_[8];                                                               \
    if (xb_ >= 0) {                                                            \
        const float4 u0_ = *(const float4*)(x + xb_);                          \
        const float4 u1_ = *(const float4*)(x + xb_ + 4);                      \
        v_[0]=u0_.x; v_[1]=u0_.y; v_[2]=u0_.z; v_[3]=u0_.w;                    \
        v_[4]=u1_.x; v_[5]=u1_.y; v_[6]=u1_.z; v_[7]=u1_.w;                    \
    } else {                                                                   \
        _Pragma("unroll")                                                      \
        for (int i = 0; i < 8; ++i) {                                          \
            int id_ = xb_ + i; id_ = (id_ < 0) ? 0 : id_;                      \
            v_[i] = x[id_];                                                    \
        }                                                                      \
    }                                                                          \
    _Pragma("unroll")                                                          \
    for (int i = 0; i < 8; ++i) xlds[row_*XROW + cb_ + i] = v_[i];             \
} while (0)

__global__ __launch_bounds__(64, 2) void hyper_gru_kernel(
    const float* __restrict__ x,     const float* __restrict__ c,    const float* __restrict__ h0,
    const float* __restrict__ w1,    const float* __restrict__ b1,
    const float* __restrict__ w2,    const float* __restrict__ b2,
    const float* __restrict__ pihw,  const float* __restrict__ pihb,
    const float* __restrict__ phhw,  const float* __restrict__ phhb,
    const float* __restrict__ pbihw, const float* __restrict__ pbihb,
    const float* __restrict__ pbhhw, const float* __restrict__ pbhhb,
    const float* __restrict__ oww,   const float* __restrict__ owb,
    float* __restrict__ out)
{
    const int blk = blockIdx.x;
    const int b   = blk / WPS;         // sample
    const int w   = blk - b * WPS;     // wave index within sample (32 waves)
    const int ln  = threadIdx.x;
    const int m16 = ln & 15;           // A row / B,D col (stream id)
    const int q   = ln >> 4;           // k-group (A/B) and D row-group
    const bool qlt2 = (q < 2);
    const bool isq2 = (q == 2);
    const int pim = rho(m16);          // permuted gate component for A row m16

    __shared__ float xlds[SPW * XROW];
    __shared__ float ylds[SPW * YROW];
    __shared__ float sp[2][3][16];     // k-half partial row sums (r,i,n)

    // ---- hypernetwork: cond MLP -> a2[8] (uniform; redundant per lane) ----
    float cv[8], a1m[8], a2m[8];
    #pragma unroll
    for (int n = 0; n < 8; ++n) cv[n] = c[b*8 + n];
    #pragma unroll
    for (int mm = 0; mm < 8; ++mm) {
        float sv = b1[mm];
        #pragma unroll
        for (int n = 0; n < 8; ++n) sv = fmaf(cv[n], w1[mm*8 + n], sv);
        a1m[mm] = (sv >= 0.f) ? sv : 0.1f * sv;
    }
    #pragma unroll
    for (int mm = 0; mm < 8; ++mm) {
        float sv = b2[mm];
        #pragma unroll
        for (int k = 0; k < 8; ++k) sv = fmaf(a1m[k], w2[mm*8 + k], sv);
        a2m[mm] = (sv >= 0.f) ? sv : 0.1f * sv;
    }
    auto proj = [&](const float* W, const float* Bv, int row) {
        float sv = Bv[row];
        #pragma unroll
        for (int mm = 0; mm < 8; ++mm) sv = fmaf(a2m[mm], W[row*8 + mm], sv);
        return sv;
    };

    // Scales folded in: r,i: -log2e (sigmoid = rcp(1+exp2(acc)));
    //                   n:   -2log2e (tanh = 2*rcp(1+exp2(acc)) - 1)
    const float SC1 = -1.44269504f, SC2 = -2.88539008f;

    // output weight fold
    float sumow = 0.f;
    #pragma unroll
    for (int k = 0; k < 16; ++k) sumow += oww[k];
    const float obv = owb[0] - sumow;

    // ---- A fragments: lane holds A[row=m16, k=8q+i] ----
    // k<16: W_hh columns (rho-permuted rows). k=16: x coeff. k=17: bias. rest 0.
    float A1f[8] = {}, A2f[8] = {}, A3f[8] = {}, A4f[8] = {};
    if (qlt2) {
        float p1 = 0.f, p2 = 0.f, p3 = 0.f;
        #pragma unroll
        for (int i = 0; i < 8; ++i) {
            const int k = 8*q + i;
            A1f[i] = SC1 * proj(phhw, phhb, k*48 + pim);        p1 += A1f[i];
            A2f[i] = SC1 * proj(phhw, phhb, k*48 + 16 + pim);   p2 += A2f[i];
            A3f[i] = SC2 * proj(phhw, phhb, k*48 + 32 + pim);   p3 += A3f[i];
            A4f[i] = (m16 == 0) ? oww[k] : 0.f;
            __builtin_amdgcn_sched_barrier(0);   // bound load-hoisting (anti-spill)
        }
        sp[q][0][m16] = p1;  sp[q][1][m16] = p2;  sp[q][2][m16] = p3;
    }
    __syncthreads();
    if (isq2) {
        const float sWr = sp[0][0][m16] + sp[1][0][m16];
        const float sWi = sp[0][1][m16] + sp[1][1][m16];
        const float sWn = sp[0][2][m16] + sp[1][2][m16];
        A1f[0] = SC1 * proj(pihw, pihb, pim);
        A1f[1] = SC1 * (proj(pbihw, pbihb, pim) + proj(pbhhw, pbhhb, pim)) - sWr;
        A2f[0] = SC1 * proj(pihw, pihb, 16 + pim);
        A2f[1] = SC1 * (proj(pbihw, pbihb, 16 + pim) + proj(pbhhw, pbhhb, 16 + pim)) - sWi;
        A3f[1] = SC2 * proj(pbhhw, pbhhb, 32 + pim) - sWn;     // biasAN (r-multiplied)
        A4f[1] = (m16 == 0) ? obv : 0.f;
        __builtin_amdgcn_sched_barrier(0);
    }
    BU A1u, A2u, A3u, A4u;
    #pragma unroll
    for (int r = 0; r < 4; ++r) {
        A1u.h2[r] = __builtin_amdgcn_cvt_pkrtz(A1f[2*r], A1f[2*r+1]);
        A2u.h2[r] = __builtin_amdgcn_cvt_pkrtz(A2f[2*r], A2f[2*r+1]);
        A3u.h2[r] = __builtin_amdgcn_cvt_pkrtz(A3f[2*r], A3f[2*r+1]);
        A4u.h2[r] = __builtin_amdgcn_cvt_pkrtz(A4f[2*r], A4f[2*r+1]);
    }

    // n-gate x-projection stays on VALU; component cj = rho(4q+j).
    float wihN4[4], bihN4[4], owN4[4];
    #pragma unroll
    for (int j = 0; j < 4; ++j) {
        const int cj = rho(4*q + j);
        wihN4[j] = SC2 * proj(pihw, pihb, 32 + cj);
        bihN4[j] = SC2 * proj(pbihw, pbihb, 32 + cj);
        owN4[j]  = oww[cj];
    }
    __builtin_amdgcn_sched_barrier(0);

    const f32x4 zero4 = {0.f, 0.f, 0.f, 0.f};

    // ---- state: H = h+1; all streams speculate 1; stream 0 re-pinned at
    // the warm->main boundary (equivalent to per-step pinning) ----
    float Hd[4];
    #pragma unroll
    for (int j = 0; j < 4; ++j) Hd[j] = 1.f;

    STAGE_X(0);
    __syncthreads();

    // Phase stagger: co-resident waves (different blocks) run an identical
    // fixed-period loop, so this one-time offset persists -> anti-phase
    // stall gaps instead of coincident ones. s_sleep arg must be a literal.
    {
        const int ph = blk & 3;
        if (ph == 1) __builtin_amdgcn_s_sleep(2);
        else if (ph == 2) __builtin_amdgcn_s_sleep(4);
        else if (ph == 3) __builtin_amdgcn_s_sleep(6);
    }

    for (int cc = 0; cc < NCH; ++cc) {
        if (cc == CSKIP && w == 0 && m16 == 0) {
            #pragma unroll
            for (int j = 0; j < 4; ++j)
                Hd[j] = h0[b*16 + rho(4*q + j)] + 1.f;
        }
        const bool doy = (cc >= CSKIP) && (ln < 16);
        const float* xr = xlds + m16*XROW;
        float xcur = xr[0];
        #pragma unroll
        for (int tt = 0; tt < 32; ++tt) GRU_STEP(tt);

        if (cc >= CSKIP) {
            // slot-31 y from current H: obv + sum_h ow[h]*H[h] (4 lanes/stream)
            float p = 0.f;
            #pragma unroll
            for (int j = 0; j < 4; ++j) p = fmaf(owN4[j], Hd[j], p);
            p += __shfl_xor(p, 16, 64);
            p += __shfl_xor(p, 32, 64);
            if (ln < 16) ylds[m16*YROW + 31] = obv + p;
        }
        __syncthreads();           // ylds complete; xlds reads done

        if (cc >= CSKIP) {
            const int s_ = ln >> 2, cb_ = (ln & 3) * 8;
            const int tb = b*T_LEN + (SPW*w + s_)*SEG + (cc - CSKIP)*32 + cb_;
            float4 o0, o1;
            o0.x = ylds[s_*YROW + cb_ + 0];
            o0.y = ylds[s_*YROW + cb_ + 1];
            o0.z = ylds[s_*YROW + cb_ + 2];
            o0.w = ylds[s_*YROW + cb_ + 3];
            o1.x = ylds[s_*YROW + cb_ + 4];
            o1.y = ylds[s_*YROW + cb_ + 5];
            o1.z = ylds[s_*YROW + cb_ + 6];
            o1.w = ylds[s_*YROW + cb_ + 7];
            *(float4*)(out + tb)     = o0;
            *(float4*)(out + tb + 4) = o1;
        }
        if (cc + 1 < NCH) STAGE_X(cc + 1);
        __syncthreads();           // xlds ready for next chunk
    }

    // h_last [B,1,R]: last stream = (w=WPS-1, m16=15); exact f32 state
    if (w == WPS - 1 && m16 == 15) {
        #pragma unroll
        for (int j = 0; j < 4; ++j)
            out[B_N * T_LEN + b*16 + rho(4*q + j)] = Hd[j] - 1.f;
    }
}

extern "C" void kernel_launch(void* const* d_in, const int* in_sizes, int n_in,
                              void* d_out, int out_size, void* d_ws, size_t ws_size,
                              hipStream_t stream) {
    (void)in_sizes; (void)n_in; (void)d_ws; (void)ws_size; (void)out_size;
    hipLaunchKernelGGL(hyper_gru_kernel, dim3(B_N * WPS), dim3(64), 0, stream,
        (const float*)d_in[0],  (const float*)d_in[1],  (const float*)d_in[2],
        (const float*)d_in[3],  (const float*)d_in[4],  (const float*)d_in[5],  (const float*)d_in[6],
        (const float*)d_in[7],  (const float*)d_in[8],  (const float*)d_in[9],  (const float*)d_in[10],
        (const float*)d_in[11], (const float*)d_in[12], (const float*)d_in[13], (const float*)d_in[14],
        (const float*)d_in[15], (const float*)d_in[16],
        (float*)d_out);
}

// Round 12
// 149.195 us; speedup vs baseline: 1.0871x; 1.0072x over previous
//
#include <hip/hip_runtime.h>

#define T_LEN 32768
#define B_N   64
#define SEG   64
#define WARM  64
#define NSEG  (T_LEN / SEG)        // 512 segments/sample
#define SPW   16                   // streams per wave (16x16 MFMA cols)
#define WPS   (NSEG / SPW)         // 32 waves/sample -> grid 2048 (8 blk/CU, 2 waves/SIMD)
#define CSKIP (WARM / 32)          // 2 warm chunks
#define NCH   (CSKIP + SEG / 32)   // 4 chunks of 32 steps
#define XROW  33                   // x LDS row stride (conflict-free)
#define YROW  33                   // y LDS row stride

typedef __fp16 half2v __attribute__((ext_vector_type(2)));
typedef __fp16 half8  __attribute__((ext_vector_type(8)));
typedef float  f32x4  __attribute__((ext_vector_type(4)));

#define MFMA16(a, b, c) __builtin_amdgcn_mfma_f32_16x16x32_f16((a), (b), (c), 0, 0, 0)

union BU { half2v h2[4]; half8 h8; int i4[4]; };

// Cross-half partner exchange lane[i] <-> lane[i^32] (r28: full-rate VALU
// permlane32_swap; r[0]^r[1]^P -> partner under either operand-order reading).
#if __has_builtin(__builtin_amdgcn_permlane32_swap)
typedef int int2v __attribute__((ext_vector_type(2)));
#define XHALF(P) ({ int2v r_ = __builtin_amdgcn_permlane32_swap((P), (P), false, false); \
                    (int)(r_[0] ^ r_[1] ^ (P)); })
#else
#define XHALF(P) __shfl_xor((P), 32, 64)
#endif

// Row permutation rho (involution): swaps 4..7 <-> 8..11. With the verified
// 16x16 D-layout (col=lane&15, row=(lane>>4)*4+reg), A-rows permuted by rho
// make lane q own H components rho(4q..4q+3), so the B-fragment rebuild is
// own-quad + (lane^32)-quad — one XHALF pair, zero other cross-lane ops.
__device__ __forceinline__ int rho(int v) {
    const int qq = v >> 2;
    return (qq == 1) ? v + 4 : (qq == 2) ? v - 4 : v;
}

// r32: TRANSCENDENTAL CUT. r11 post-mortem: issue/wave-step ~400 cy, of
// which ~384 is the 24 quarter-rate transcendentals (3 gates x 4 comps x
// {exp2, rcp}) — the kernel is trans-pipe-issue-bound, not stall-bound
// (stagger was null). Two EXACT algebraic rewrites cut 24 -> 16 trans:
//  (1) fused i/n update: H' = ui(H-2un)+2un with ui=1/(1+z), un=1/(1+y)
//      == [H(1+y) + 2z] / [(1+y)(1+z)]  -> ONE rcp per component;
//  (2) pair-merged reciprocals: 1/a,1/b from one rcp(a*b) (ur pair and
//      fused-denominator pair). exp2 args are small hypernet preacts
//      (factors <= 2^15, products safely in f32 range); rcp err ~1e-7
//      << f16-pack rounding. r9 structure (best, 68.6us) otherwise kept;
//      r11's null stagger dropped. Segment-parallel correctness (r12)
//      unchanged: WARM=64, boundary re-pin.
#define GRU_STEP(TT) do {                                                      \
    half2v t0_ = __builtin_amdgcn_cvt_pkrtz(Hd[0], Hd[1]);                     \
    half2v t1_ = __builtin_amdgcn_cvt_pkrtz(Hd[2], Hd[3]);                     \
    int p0_, p1_;                                                              \
    __builtin_memcpy(&p0_, &t0_, 4); __builtin_memcpy(&p1_, &t1_, 4);          \
    const int pp0_ = XHALF(p0_);                                               \
    const int pp1_ = XHALF(p1_);                                               \
    half2v tx_ = __builtin_amdgcn_cvt_pkrtz(xcur, 1.0f);                       \
    int xw_; __builtin_memcpy(&xw_, &tx_, 4);                                  \
    BU Bu_;                                                                    \
    Bu_.i4[0] = qlt2 ? p0_ : (isq2 ? xw_ : 0);                                 \
    Bu_.i4[1] = qlt2 ? p1_ : 0;                                                \
    Bu_.i4[2] = qlt2 ? pp0_ : 0;                                               \
    Bu_.i4[3] = qlt2 ? pp1_ : 0;                                               \
    const f32x4 d1 = MFMA16(A1u.h8, Bu_.h8, zero4);                            \
    const f32x4 d2 = MFMA16(A2u.h8, Bu_.h8, zero4);                            \
    const f32x4 d3 = MFMA16(A3u.h8, Bu_.h8, zero4);                            \
    const f32x4 d4 = MFMA16(A4u.h8, Bu_.h8, zero4);                            \
    const float xnx_ = xr[((TT) + 1 < 32) ? (TT) + 1 : 31];                    \
    _Pragma("unroll")                                                          \
    for (int jp = 0; jp < 2; ++jp) {                                           \
        const int j0 = 2*jp, j1 = 2*jp + 1;                                    \
        const float a0 = 1.f + __builtin_amdgcn_exp2f(d1[j0]);                 \
        const float a1 = 1.f + __builtin_amdgcn_exp2f(d1[j1]);                 \
        const float rP = __builtin_amdgcn_rcpf(a0 * a1);                       \
        const float ur0 = rP * a1, ur1 = rP * a0;                              \
        const float z0 = __builtin_amdgcn_exp2f(d2[j0]);                       \
        const float z1 = __builtin_amdgcn_exp2f(d2[j1]);                       \
        const float tno0 = fmaf(ur0, d3[j0], fmaf(xcur, wihN4[j0], bihN4[j0]));\
        const float tno1 = fmaf(ur1, d3[j1], fmaf(xcur, wihN4[j1], bihN4[j1]));\
        const float e0 = 1.f + __builtin_amdgcn_exp2f(tno0);                   \
        const float e1 = 1.f + __builtin_amdgcn_exp2f(tno1);                   \
        const float den0 = e0 * (1.f + z0), den1 = e1 * (1.f + z1);            \
        const float rQ = __builtin_amdgcn_rcpf(den0 * den1);                   \
        const float rd0 = rQ * den1, rd1 = rQ * den0;                          \
        Hd[j0] = fmaf(Hd[j0], e0, z0 + z0) * rd0;                              \
        Hd[j1] = fmaf(Hd[j1], e1, z1 + z1) * rd1;                              \
    }                                                                          \
    if (doy) ylds[m16*YROW + (((TT) + 31) & 31)] = d4[0];                      \
    xcur = xnx_;                                                               \
} while (0)

// x staging: 16 streams x 32 steps per chunk; lane ln>>2 = row, 8 floats
#define STAGE_X(CC) do {                                                       \
    const int row_ = ln >> 2, cb_ = (ln & 3) * 8;                              \
    const int xb_ = b*T_LEN + (SPW*w + row_)*SEG - WARM + (CC)*32 + cb_;       \
    float v_[8];                                                               \
    if (xb_ >= 0) {                                                            \
        const float4 u0_ = *(const float4*)(x + xb_);                          \
        const float4 u1_ = *(const float4*)(x + xb_ + 4);                      \
        v_[0]=u0_.x; v_[1]=u0_.y; v_[2]=u0_.z; v_[3]=u0_.w;                    \
        v_[4]=u1_.x; v_[5]=u1_.y; v_[6]=u1_.z; v_[7]=u1_.w;                    \
    } else {                                                                   \
        _Pragma("unroll")                                                      \
        for (int i = 0; i < 8; ++i) {                                          \
            int id_ = xb_ + i; id_ = (id_ < 0) ? 0 : id_;                      \
            v_[i] = x[id_];                                                    \
        }                                                                      \
    }                                                                          \
    _Pragma("unroll")                                                          \
    for (int i = 0; i < 8; ++i) xlds[row_*XROW + cb_ + i] = v_[i];             \
} while (0)

__global__ __launch_bounds__(64, 2) void hyper_gru_kernel(
    const float* __restrict__ x,     const float* __restrict__ c,    const float* __restrict__ h0,
    const float* __restrict__ w1,    const float* __restrict__ b1,
    const float* __restrict__ w2,    const float* __restrict__ b2,
    const float* __restrict__ pihw,  const float* __restrict__ pihb,
    const float* __restrict__ phhw,  const float* __restrict__ phhb,
    const float* __restrict__ pbihw, const float* __restrict__ pbihb,
    const float* __restrict__ pbhhw, const float* __restrict__ pbhhb,
    const float* __restrict__ oww,   const float* __restrict__ owb,
    float* __restrict__ out)
{
    const int blk = blockIdx.x;
    const int b   = blk / WPS;         // sample
    const int w   = blk - b * WPS;     // wave index within sample (32 waves)
    const int ln  = threadIdx.x;
    const int m16 = ln & 15;           // A row / B,D col (stream id)
    const int q   = ln >> 4;           // k-group (A/B) and D row-group
    const bool qlt2 = (q < 2);
    const bool isq2 = (q == 2);
    const int pim = rho(m16);          // permuted gate component for A row m16

    __shared__ float xlds[SPW * XROW];
    __shared__ float ylds[SPW * YROW];
    __shared__ float sp[2][3][16];     // k-half partial row sums (r,i,n)

    // ---- hypernetwork: cond MLP -> a2[8] (uniform; redundant per lane) ----
    float cv[8], a1m[8], a2m[8];
    #pragma unroll
    for (int n = 0; n < 8; ++n) cv[n] = c[b*8 + n];
    #pragma unroll
    for (int mm = 0; mm < 8; ++mm) {
        float sv = b1[mm];
        #pragma unroll
        for (int n = 0; n < 8; ++n) sv = fmaf(cv[n], w1[mm*8 + n], sv);
        a1m[mm] = (sv >= 0.f) ? sv : 0.1f * sv;
    }
    #pragma unroll
    for (int mm = 0; mm < 8; ++mm) {
        float sv = b2[mm];
        #pragma unroll
        for (int k = 0; k < 8; ++k) sv = fmaf(a1m[k], w2[mm*8 + k], sv);
        a2m[mm] = (sv >= 0.f) ? sv : 0.1f * sv;
    }
    auto proj = [&](const float* W, const float* Bv, int row) {
        float sv = Bv[row];
        #pragma unroll
        for (int mm = 0; mm < 8; ++mm) sv = fmaf(a2m[mm], W[row*8 + mm], sv);
        return sv;
    };

    // Scales folded in: r,i: -log2e (sigmoid = rcp(1+exp2(acc)));
    //                   n:   -2log2e (tanh = 2*rcp(1+exp2(acc)) - 1)
    const float SC1 = -1.44269504f, SC2 = -2.88539008f;

    // output weight fold
    float sumow = 0.f;
    #pragma unroll
    for (int k = 0; k < 16; ++k) sumow += oww[k];
    const float obv = owb[0] - sumow;

    // ---- A fragments: lane holds A[row=m16, k=8q+i] ----
    // k<16: W_hh columns (rho-permuted rows). k=16: x coeff. k=17: bias. rest 0.
    float A1f[8] = {}, A2f[8] = {}, A3f[8] = {}, A4f[8] = {};
    if (qlt2) {
        float p1 = 0.f, p2 = 0.f, p3 = 0.f;
        #pragma unroll
        for (int i = 0; i < 8; ++i) {
            const int k = 8*q + i;
            A1f[i] = SC1 * proj(phhw, phhb, k*48 + pim);        p1 += A1f[i];
            A2f[i] = SC1 * proj(phhw, phhb, k*48 + 16 + pim);   p2 += A2f[i];
            A3f[i] = SC2 * proj(phhw, phhb, k*48 + 32 + pim);   p3 += A3f[i];
            A4f[i] = (m16 == 0) ? oww[k] : 0.f;
            __builtin_amdgcn_sched_barrier(0);   // bound load-hoisting (anti-spill)
        }
        sp[q][0][m16] = p1;  sp[q][1][m16] = p2;  sp[q][2][m16] = p3;
    }
    __syncthreads();
    if (isq2) {
        const float sWr = sp[0][0][m16] + sp[1][0][m16];
        const float sWi = sp[0][1][m16] + sp[1][1][m16];
        const float sWn = sp[0][2][m16] + sp[1][2][m16];
        A1f[0] = SC1 * proj(pihw, pihb, pim);
        A1f[1] = SC1 * (proj(pbihw, pbihb, pim) + proj(pbhhw, pbhhb, pim)) - sWr;
        A2f[0] = SC1 * proj(pihw, pihb, 16 + pim);
        A2f[1] = SC1 * (proj(pbihw, pbihb, 16 + pim) + proj(pbhhw, pbhhb, 16 + pim)) - sWi;
        A3f[1] = SC2 * proj(pbhhw, pbhhb, 32 + pim) - sWn;     // biasAN (r-multiplied)
        A4f[1] = (m16 == 0) ? obv : 0.f;
        __builtin_amdgcn_sched_barrier(0);
    }
    BU A1u, A2u, A3u, A4u;
    #pragma unroll
    for (int r = 0; r < 4; ++r) {
        A1u.h2[r] = __builtin_amdgcn_cvt_pkrtz(A1f[2*r], A1f[2*r+1]);
        A2u.h2[r] = __builtin_amdgcn_cvt_pkrtz(A2f[2*r], A2f[2*r+1]);
        A3u.h2[r] = __builtin_amdgcn_cvt_pkrtz(A3f[2*r], A3f[2*r+1]);
        A4u.h2[r] = __builtin_amdgcn_cvt_pkrtz(A4f[2*r], A4f[2*r+1]);
    }

    // n-gate x-projection stays on VALU; component cj = rho(4q+j).
    float wihN4[4], bihN4[4], owN4[4];
    #pragma unroll
    for (int j = 0; j < 4; ++j) {
        const int cj = rho(4*q + j);
        wihN4[j] = SC2 * proj(pihw, pihb, 32 + cj);
        bihN4[j] = SC2 * proj(pbihw, pbihb, 32 + cj);
        owN4[j]  = oww[cj];
    }
    __builtin_amdgcn_sched_barrier(0);

    const f32x4 zero4 = {0.f, 0.f, 0.f, 0.f};

    // ---- state: H = h+1; all streams speculate 1; stream 0 re-pinned at
    // the warm->main boundary (equivalent to per-step pinning) ----
    float Hd[4];
    #pragma unroll
    for (int j = 0; j < 4; ++j) Hd[j] = 1.f;

    STAGE_X(0);
    __syncthreads();

    for (int cc = 0; cc < NCH; ++cc) {
        if (cc == CSKIP && w == 0 && m16 == 0) {
            #pragma unroll
            for (int j = 0; j < 4; ++j)
                Hd[j] = h0[b*16 + rho(4*q + j)] + 1.f;
        }
        const bool doy = (cc >= CSKIP) && (ln < 16);
        const float* xr = xlds + m16*XROW;
        float xcur = xr[0];
        #pragma unroll
        for (int tt = 0; tt < 32; ++tt) GRU_STEP(tt);

        if (cc >= CSKIP) {
            // slot-31 y from current H: obv + sum_h ow[h]*H[h] (4 lanes/stream)
            float p = 0.f;
            #pragma unroll
            for (int j = 0; j < 4; ++j) p = fmaf(owN4[j], Hd[j], p);
            p += __shfl_xor(p, 16, 64);
            p += __shfl_xor(p, 32, 64);
            if (ln < 16) ylds[m16*YROW + 31] = obv + p;
        }
        __syncthreads();           // ylds complete; xlds reads done

        if (cc >= CSKIP) {
            const int s_ = ln >> 2, cb_ = (ln & 3) * 8;
            const int tb = b*T_LEN + (SPW*w + s_)*SEG + (cc - CSKIP)*32 + cb_;
            float4 o0, o1;
            o0.x = ylds[s_*YROW + cb_ + 0];
            o0.y = ylds[s_*YROW + cb_ + 1];
            o0.z = ylds[s_*YROW + cb_ + 2];
            o0.w = ylds[s_*YROW + cb_ + 3];
            o1.x = ylds[s_*YROW + cb_ + 4];
            o1.y = ylds[s_*YROW + cb_ + 5];
            o1.z = ylds[s_*YROW + cb_ + 6];
            o1.w = ylds[s_*YROW + cb_ + 7];
            *(float4*)(out + tb)     = o0;
            *(float4*)(out + tb + 4) = o1;
        }
        if (cc + 1 < NCH) STAGE_X(cc + 1);
        __syncthreads();           // xlds ready for next chunk
    }

    // h_last [B,1,R]: last stream = (w=WPS-1, m16=15); exact f32 state
    if (w == WPS - 1 && m16 == 15) {
        #pragma unroll
        for (int j = 0; j < 4; ++j)
            out[B_N * T_LEN + b*16 + rho(4*q + j)] = Hd[j] - 1.f;
    }
}

extern "C" void kernel_launch(void* const* d_in, const int* in_sizes, int n_in,
                              void* d_out, int out_size, void* d_ws, size_t ws_size,
                              hipStream_t stream) {
    (void)in_sizes; (void)n_in; (void)d_ws; (void)ws_size; (void)out_size;
    hipLaunchKernelGGL(hyper_gru_kernel, dim3(B_N * WPS), dim3(64), 0, stream,
        (const float*)d_in[0],  (const float*)d_in[1],  (const float*)d_in[2],
        (const float*)d_in[3],  (const float*)d_in[4],  (const float*)d_in[5],  (const float*)d_in[6],
        (const float*)d_in[7],  (const float*)d_in[8],  (const float*)d_in[9],  (const float*)d_in[10],
        (const float*)d_in[11], (const float*)d_in[12], (const float*)d_in[13], (const float*)d_in[14],
        (const float*)d_in[15], (const float*)d_in[16],
        (float*)d_out);
}

// Round 13
// 144.661 us; speedup vs baseline: 1.1212x; 1.0313x over previous
//
#include <hip/hip_runtime.h>

#define T_LEN 32768
#define B_N   64
#define SEG   64
#define WARM  64
#define NSEG  (T_LEN / SEG)        // 512 segments/sample
#define SPW   16                   // streams per wave (16x16 MFMA cols)
#define WPS   (NSEG / SPW)         // 32 waves/sample -> grid 2048 (8 blk/CU, 2 waves/SIMD)
#define CSKIP (WARM / 32)          // 2 warm chunks
#define NCH   (CSKIP + SEG / 32)   // 4 chunks of 32 steps
#define XROW  33                   // x LDS row stride (conflict-free)
#define YROW  33                   // y LDS row stride

typedef __fp16 half2v __attribute__((ext_vector_type(2)));
typedef __fp16 half8  __attribute__((ext_vector_type(8)));
typedef float  f32x4  __attribute__((ext_vector_type(4)));

#define MFMA16(a, b, c) __builtin_amdgcn_mfma_f32_16x16x32_f16((a), (b), (c), 0, 0, 0)

union BU { half2v h2[4]; half8 h8; int i4[4]; };

// Cross-half partner exchange lane[i] <-> lane[i^32] (r28: full-rate VALU
// permlane32_swap; r[0]^r[1]^P -> partner under either operand-order reading).
#if __has_builtin(__builtin_amdgcn_permlane32_swap)
typedef int int2v __attribute__((ext_vector_type(2)));
#define XHALF(P) ({ int2v r_ = __builtin_amdgcn_permlane32_swap((P), (P), false, false); \
                    (int)(r_[0] ^ r_[1] ^ (P)); })
#else
#define XHALF(P) __shfl_xor((P), 32, 64)
#endif

// Row permutation rho (involution): swaps 4..7 <-> 8..11. With the verified
// 16x16 D-layout (col=lane&15, row=(lane>>4)*4+reg), A-rows permuted by rho
// make lane q own H components rho(4q..4q+3), so the B-fragment rebuild is
// own-quad + (lane^32)-quad — one XHALF pair, zero other cross-lane ops.
__device__ __forceinline__ int rho(int v) {
    const int qq = v >> 2;
    return (qq == 1) ? v + 4 : (qq == 2) ? v - 4 : v;
}

// r33: I-CACHE FIT. r12 post-mortem: wall is 1251 cy/wave-step but issue is
// only ~363 cy and the data chain ~300-400 cy; scheduling experiments all
// null. The 32-step FULLY-unrolled body is ~150 instr x 32 ~ 38 KB — LARGER
// than the 32 KB per-CU L1I. Both co-resident waves stream code from L2
// every chunk (and r10's 76 KB dual-group body regressed fill — same
// signature). Fix: #pragma unroll 4 -> ~5 KB hot body, fits L1I; costs a
// few full-rate ops for dynamic tt indexing. Math bit-identical to r12
// (16 trans/step: fused i/n rcp + pair-merged rcp; 16x16x32 MFMA shape;
// permlane XHALF). Segment-parallel correctness (r12) unchanged: WARM=64,
// boundary re-pin.
#define GRU_STEP(TT) do {                                                      \
    half2v t0_ = __builtin_amdgcn_cvt_pkrtz(Hd[0], Hd[1]);                     \
    half2v t1_ = __builtin_amdgcn_cvt_pkrtz(Hd[2], Hd[3]);                     \
    int p0_, p1_;                                                              \
    __builtin_memcpy(&p0_, &t0_, 4); __builtin_memcpy(&p1_, &t1_, 4);          \
    const int pp0_ = XHALF(p0_);                                               \
    const int pp1_ = XHALF(p1_);                                               \
    half2v tx_ = __builtin_amdgcn_cvt_pkrtz(xcur, 1.0f);                       \
    int xw_; __builtin_memcpy(&xw_, &tx_, 4);                                  \
    BU Bu_;                                                                    \
    Bu_.i4[0] = qlt2 ? p0_ : (isq2 ? xw_ : 0);                                 \
    Bu_.i4[1] = qlt2 ? p1_ : 0;                                                \
    Bu_.i4[2] = qlt2 ? pp0_ : 0;                                               \
    Bu_.i4[3] = qlt2 ? pp1_ : 0;                                               \
    const f32x4 d1 = MFMA16(A1u.h8, Bu_.h8, zero4);                            \
    const f32x4 d2 = MFMA16(A2u.h8, Bu_.h8, zero4);                            \
    const f32x4 d3 = MFMA16(A3u.h8, Bu_.h8, zero4);                            \
    const f32x4 d4 = MFMA16(A4u.h8, Bu_.h8, zero4);                            \
    const int nxi_ = (TT) + 1;                                                 \
    const float xnx_ = xr[nxi_ < 32 ? nxi_ : 31];                              \
    _Pragma("unroll")                                                          \
    for (int jp = 0; jp < 2; ++jp) {                                           \
        const int j0 = 2*jp, j1 = 2*jp + 1;                                    \
        const float a0 = 1.f + __builtin_amdgcn_exp2f(d1[j0]);                 \
        const float a1 = 1.f + __builtin_amdgcn_exp2f(d1[j1]);                 \
        const float rP = __builtin_amdgcn_rcpf(a0 * a1);                       \
        const float ur0 = rP * a1, ur1 = rP * a0;                              \
        const float z0 = __builtin_amdgcn_exp2f(d2[j0]);                       \
        const float z1 = __builtin_amdgcn_exp2f(d2[j1]);                       \
        const float tno0 = fmaf(ur0, d3[j0], fmaf(xcur, wihN4[j0], bihN4[j0]));\
        const float tno1 = fmaf(ur1, d3[j1], fmaf(xcur, wihN4[j1], bihN4[j1]));\
        const float e0 = 1.f + __builtin_amdgcn_exp2f(tno0);                   \
        const float e1 = 1.f + __builtin_amdgcn_exp2f(tno1);                   \
        const float den0 = e0 * (1.f + z0), den1 = e1 * (1.f + z1);            \
        const float rQ = __builtin_amdgcn_rcpf(den0 * den1);                   \
        const float rd0 = rQ * den1, rd1 = rQ * den0;                          \
        Hd[j0] = fmaf(Hd[j0], e0, z0 + z0) * rd0;                              \
        Hd[j1] = fmaf(Hd[j1], e1, z1 + z1) * rd1;                              \
    }                                                                          \
    if (doy) ylds[m16*YROW + (((TT) + 31) & 31)] = d4[0];                      \
    xcur = xnx_;                                                               \
} while (0)

// x staging: 16 streams x 32 steps per chunk; lane ln>>2 = row, 8 floats
#define STAGE_X(CC) do {                                                       \
    const int row_ = ln >> 2, cb_ = (ln & 3) * 8;                              \
    const int xb_ = b*T_LEN + (SPW*w + row_)*SEG - WARM + (CC)*32 + cb_;       \
    float v_[8];                                                               \
    if (xb_ >= 0) {                                                            \
        const float4 u0_ = *(const float4*)(x + xb_);                          \
        const float4 u1_ = *(const float4*)(x + xb_ + 4);                      \
        v_[0]=u0_.x; v_[1]=u0_.y; v_[2]=u0_.z; v_[3]=u0_.w;                    \
        v_[4]=u1_.x; v_[5]=u1_.y; v_[6]=u1_.z; v_[7]=u1_.w;                    \
    } else {                                                                   \
        _Pragma("unroll")                                                      \
        for (int i = 0; i < 8; ++i) {                                          \
            int id_ = xb_ + i; id_ = (id_ < 0) ? 0 : id_;                      \
            v_[i] = x[id_];                                                    \
        }                                                                      \
    }                                                                          \
    _Pragma("unroll")                                                          \
    for (int i = 0; i < 8; ++i) xlds[row_*XROW + cb_ + i] = v_[i];             \
} while (0)

__global__ __launch_bounds__(64, 2) void hyper_gru_kernel(
    const float* __restrict__ x,     const float* __restrict__ c,    const float* __restrict__ h0,
    const float* __restrict__ w1,    const float* __restrict__ b1,
    const float* __restrict__ w2,    const float* __restrict__ b2,
    const float* __restrict__ pihw,  const float* __restrict__ pihb,
    const float* __restrict__ phhw,  const float* __restrict__ phhb,
    const float* __restrict__ pbihw, const float* __restrict__ pbihb,
    const float* __restrict__ pbhhw, const float* __restrict__ pbhhb,
    const float* __restrict__ oww,   const float* __restrict__ owb,
    float* __restrict__ out)
{
    const int blk = blockIdx.x;
    const int b   = blk / WPS;         // sample
    const int w   = blk - b * WPS;     // wave index within sample (32 waves)
    const int ln  = threadIdx.x;
    const int m16 = ln & 15;           // A row / B,D col (stream id)
    const int q   = ln >> 4;           // k-group (A/B) and D row-group
    const bool qlt2 = (q < 2);
    const bool isq2 = (q == 2);
    const int pim = rho(m16);          // permuted gate component for A row m16

    __shared__ float xlds[SPW * XROW];
    __shared__ float ylds[SPW * YROW];
    __shared__ float sp[2][3][16];     // k-half partial row sums (r,i,n)

    // ---- hypernetwork: cond MLP -> a2[8] (uniform; redundant per lane) ----
    float cv[8], a1m[8], a2m[8];
    #pragma unroll
    for (int n = 0; n < 8; ++n) cv[n] = c[b*8 + n];
    #pragma unroll
    for (int mm = 0; mm < 8; ++mm) {
        float sv = b1[mm];
        #pragma unroll
        for (int n = 0; n < 8; ++n) sv = fmaf(cv[n], w1[mm*8 + n], sv);
        a1m[mm] = (sv >= 0.f) ? sv : 0.1f * sv;
    }
    #pragma unroll
    for (int mm = 0; mm < 8; ++mm) {
        float sv = b2[mm];
        #pragma unroll
        for (int k = 0; k < 8; ++k) sv = fmaf(a1m[k], w2[mm*8 + k], sv);
        a2m[mm] = (sv >= 0.f) ? sv : 0.1f * sv;
    }
    auto proj = [&](const float* W, const float* Bv, int row) {
        float sv = Bv[row];
        #pragma unroll
        for (int mm = 0; mm < 8; ++mm) sv = fmaf(a2m[mm], W[row*8 + mm], sv);
        return sv;
    };

    // Scales folded in: r,i: -log2e (sigmoid = rcp(1+exp2(acc)));
    //                   n:   -2log2e (tanh = 2*rcp(1+exp2(acc)) - 1)
    const float SC1 = -1.44269504f, SC2 = -2.88539008f;

    // output weight fold
    float sumow = 0.f;
    #pragma unroll
    for (int k = 0; k < 16; ++k) sumow += oww[k];
    const float obv = owb[0] - sumow;

    // ---- A fragments: lane holds A[row=m16, k=8q+i] ----
    // k<16: W_hh columns (rho-permuted rows). k=16: x coeff. k=17: bias. rest 0.
    float A1f[8] = {}, A2f[8] = {}, A3f[8] = {}, A4f[8] = {};
    if (qlt2) {
        float p1 = 0.f, p2 = 0.f, p3 = 0.f;
        #pragma unroll
        for (int i = 0; i < 8; ++i) {
            const int k = 8*q + i;
            A1f[i] = SC1 * proj(phhw, phhb, k*48 + pim);        p1 += A1f[i];
            A2f[i] = SC1 * proj(phhw, phhb, k*48 + 16 + pim);   p2 += A2f[i];
            A3f[i] = SC2 * proj(phhw, phhb, k*48 + 32 + pim);   p3 += A3f[i];
            A4f[i] = (m16 == 0) ? oww[k] : 0.f;
            __builtin_amdgcn_sched_barrier(0);   // bound load-hoisting (anti-spill)
        }
        sp[q][0][m16] = p1;  sp[q][1][m16] = p2;  sp[q][2][m16] = p3;
    }
    __syncthreads();
    if (isq2) {
        const float sWr = sp[0][0][m16] + sp[1][0][m16];
        const float sWi = sp[0][1][m16] + sp[1][1][m16];
        const float sWn = sp[0][2][m16] + sp[1][2][m16];
        A1f[0] = SC1 * proj(pihw, pihb, pim);
        A1f[1] = SC1 * (proj(pbihw, pbihb, pim) + proj(pbhhw, pbhhb, pim)) - sWr;
        A2f[0] = SC1 * proj(pihw, pihb, 16 + pim);
        A2f[1] = SC1 * (proj(pbihw, pbihb, 16 + pim) + proj(pbhhw, pbhhb, 16 + pim)) - sWi;
        A3f[1] = SC2 * proj(pbhhw, pbhhb, 32 + pim) - sWn;     // biasAN (r-multiplied)
        A4f[1] = (m16 == 0) ? obv : 0.f;
        __builtin_amdgcn_sched_barrier(0);
    }
    BU A1u, A2u, A3u, A4u;
    #pragma unroll
    for (int r = 0; r < 4; ++r) {
        A1u.h2[r] = __builtin_amdgcn_cvt_pkrtz(A1f[2*r], A1f[2*r+1]);
        A2u.h2[r] = __builtin_amdgcn_cvt_pkrtz(A2f[2*r], A2f[2*r+1]);
        A3u.h2[r] = __builtin_amdgcn_cvt_pkrtz(A3f[2*r], A3f[2*r+1]);
        A4u.h2[r] = __builtin_amdgcn_cvt_pkrtz(A4f[2*r], A4f[2*r+1]);
    }

    // n-gate x-projection stays on VALU; component cj = rho(4q+j).
    float wihN4[4], bihN4[4], owN4[4];
    #pragma unroll
    for (int j = 0; j < 4; ++j) {
        const int cj = rho(4*q + j);
        wihN4[j] = SC2 * proj(pihw, pihb, 32 + cj);
        bihN4[j] = SC2 * proj(pbihw, pbihb, 32 + cj);
        owN4[j]  = oww[cj];
    }
    __builtin_amdgcn_sched_barrier(0);

    const f32x4 zero4 = {0.f, 0.f, 0.f, 0.f};

    // ---- state: H = h+1; all streams speculate 1; stream 0 re-pinned at
    // the warm->main boundary (equivalent to per-step pinning) ----
    float Hd[4];
    #pragma unroll
    for (int j = 0; j < 4; ++j) Hd[j] = 1.f;

    STAGE_X(0);
    __syncthreads();

    for (int cc = 0; cc < NCH; ++cc) {
        if (cc == CSKIP && w == 0 && m16 == 0) {
            #pragma unroll
            for (int j = 0; j < 4; ++j)
                Hd[j] = h0[b*16 + rho(4*q + j)] + 1.f;
        }
        const bool doy = (cc >= CSKIP) && (ln < 16);
        const float* xr = xlds + m16*XROW;
        float xcur = xr[0];
        #pragma unroll 4
        for (int tt = 0; tt < 32; ++tt) GRU_STEP(tt);   // r33: PARTIAL unroll — body fits L1I

        if (cc >= CSKIP) {
            // slot-31 y from current H: obv + sum_h ow[h]*H[h] (4 lanes/stream)
            float p = 0.f;
            #pragma unroll
            for (int j = 0; j < 4; ++j) p = fmaf(owN4[j], Hd[j], p);
            p += __shfl_xor(p, 16, 64);
            p += __shfl_xor(p, 32, 64);
            if (ln < 16) ylds[m16*YROW + 31] = obv + p;
        }
        __syncthreads();           // ylds complete; xlds reads done

        if (cc >= CSKIP) {
            const int s_ = ln >> 2, cb_ = (ln & 3) * 8;
            const int tb = b*T_LEN + (SPW*w + s_)*SEG + (cc - CSKIP)*32 + cb_;
            float4 o0, o1;
            o0.x = ylds[s_*YROW + cb_ + 0];
            o0.y = ylds[s_*YROW + cb_ + 1];
            o0.z = ylds[s_*YROW + cb_ + 2];
            o0.w = ylds[s_*YROW + cb_ + 3];
            o1.x = ylds[s_*YROW + cb_ + 4];
            o1.y = ylds[s_*YROW + cb_ + 5];
            o1.z = ylds[s_*YROW + cb_ + 6];
            o1.w = ylds[s_*YROW + cb_ + 7];
            *(float4*)(out + tb)     = o0;
            *(float4*)(out + tb + 4) = o1;
        }
        if (cc + 1 < NCH) STAGE_X(cc + 1);
        __syncthreads();           // xlds ready for next chunk
    }

    // h_last [B,1,R]: last stream = (w=WPS-1, m16=15); exact f32 state
    if (w == WPS - 1 && m16 == 15) {
        #pragma unroll
        for (int j = 0; j < 4; ++j)
            out[B_N * T_LEN + b*16 + rho(4*q + j)] = Hd[j] - 1.f;
    }
}

extern "C" void kernel_launch(void* const* d_in, const int* in_sizes, int n_in,
                              void* d_out, int out_size, void* d_ws, size_t ws_size,
                              hipStream_t stream) {
    (void)in_sizes; (void)n_in; (void)d_ws; (void)ws_size; (void)out_size;
    hipLaunchKernelGGL(hyper_gru_kernel, dim3(B_N * WPS), dim3(64), 0, stream,
        (const float*)d_in[0],  (const float*)d_in[1],  (const float*)d_in[2],
        (const float*)d_in[3],  (const float*)d_in[4],  (const float*)d_in[5],  (const float*)d_in[6],
        (const float*)d_in[7],  (const float*)d_in[8],  (const float*)d_in[9],  (const float*)d_in[10],
        (const float*)d_in[11], (const float*)d_in[12], (const float*)d_in[13], (const float*)d_in[14],
        (const float*)d_in[15], (const float*)d_in[16],
        (float*)d_out);
}